// Round 12
// baseline (212.375 us; speedup 1.0000x reference)
//
#include <hip/hip_runtime.h>
#include <stdint.h>

typedef signed char i8;
typedef unsigned char u8;
typedef __attribute__((ext_vector_type(4))) int i32x4;

__device__ __forceinline__ void gload_lds16(const void* g, void* l) {
  __builtin_amdgcn_global_load_lds(
      (__attribute__((address_space(1))) void*)const_cast<void*>(g),
      (__attribute__((address_space(3))) void*)l, 16, 0, 0);
}

// ---------- prep: per-row absmax quant of x (f32 [rows][4096] -> i8 + scale) ----------
__global__ __launch_bounds__(256) void k_quant_x(const float* __restrict__ in,
                                                 i8* __restrict__ out,
                                                 float* __restrict__ scale) {
  const int row = blockIdx.x, t = threadIdx.x;
  const float* src = in + (size_t)row * 4096;
  float4 v[4];
  float m = 0.f;
#pragma unroll
  for (int j = 0; j < 4; ++j) {
    v[j] = *(const float4*)(src + j * 1024 + t * 4);
    m = fmaxf(m, fmaxf(fmaxf(fabsf(v[j].x), fabsf(v[j].y)),
                       fmaxf(fabsf(v[j].z), fabsf(v[j].w))));
  }
#pragma unroll
  for (int off = 32; off; off >>= 1) m = fmaxf(m, __shfl_xor(m, off));
  __shared__ float wmax[4];
  if ((t & 63) == 0) wmax[t >> 6] = m;
  __syncthreads();
  m = fmaxf(fmaxf(wmax[0], wmax[1]), fmaxf(wmax[2], wmax[3]));
  const float inv = m > 0.f ? 127.f / m : 0.f;
  if (t == 0) scale[row] = m / 127.f;
#pragma unroll
  for (int j = 0; j < 4; ++j) {
    int q0 = (int)rintf(fmaxf(fminf(v[j].x * inv, 127.f), -127.f));
    int q1 = (int)rintf(fmaxf(fminf(v[j].y * inv, 127.f), -127.f));
    int q2 = (int)rintf(fmaxf(fminf(v[j].z * inv, 127.f), -127.f));
    int q3 = (int)rintf(fmaxf(fminf(v[j].w * inv, 127.f), -127.f));
    uint32_t p = (q0 & 255) | ((q1 & 255) << 8) | ((q2 & 255) << 16) | ((q3 & 255) << 24);
    *(uint32_t*)(out + (size_t)row * 4096 + j * 1024 + t * 4) = p;
  }
}

// ---------- prep: W' = W + 4*B@A, per-row quant to i8 + scale ----------
__global__ __launch_bounds__(256) void k_quant_w(const float* __restrict__ W,
                                                 const float* __restrict__ Am,
                                                 const float* __restrict__ Bm,
                                                 i8* __restrict__ out,
                                                 float* __restrict__ scale) {
  const int o = blockIdx.x, t = threadIdx.x;
  const float4 b4 = *(const float4*)(Bm + (o << 2));
  float4 v[4];
  float m = 0.f;
#pragma unroll
  for (int j = 0; j < 4; ++j) {
    const int i = j * 1024 + t * 4;
    float4 w  = *(const float4*)(W + ((size_t)o << 12) + i);
    float4 a0 = *(const float4*)(Am + i);
    float4 a1 = *(const float4*)(Am + 4096 + i);
    float4 a2 = *(const float4*)(Am + 8192 + i);
    float4 a3 = *(const float4*)(Am + 12288 + i);
    w.x += 4.f * (b4.x * a0.x + b4.y * a1.x + b4.z * a2.x + b4.w * a3.x);
    w.y += 4.f * (b4.x * a0.y + b4.y * a1.y + b4.z * a2.y + b4.w * a3.y);
    w.z += 4.f * (b4.x * a0.z + b4.y * a1.z + b4.z * a2.z + b4.w * a3.z);
    w.w += 4.f * (b4.x * a0.w + b4.y * a1.w + b4.z * a2.w + b4.w * a3.w);
    v[j] = w;
    m = fmaxf(m, fmaxf(fmaxf(fabsf(w.x), fabsf(w.y)), fmaxf(fabsf(w.z), fabsf(w.w))));
  }
#pragma unroll
  for (int off = 32; off; off >>= 1) m = fmaxf(m, __shfl_xor(m, off));
  __shared__ float wmax[4];
  if ((t & 63) == 0) wmax[t >> 6] = m;
  __syncthreads();
  m = fmaxf(fmaxf(wmax[0], wmax[1]), fmaxf(wmax[2], wmax[3]));
  const float inv = m > 0.f ? 127.f / m : 0.f;
  if (t == 0) scale[o] = m / 127.f;
#pragma unroll
  for (int j = 0; j < 4; ++j) {
    int q0 = (int)rintf(fmaxf(fminf(v[j].x * inv, 127.f), -127.f));
    int q1 = (int)rintf(fmaxf(fminf(v[j].y * inv, 127.f), -127.f));
    int q2 = (int)rintf(fmaxf(fminf(v[j].z * inv, 127.f), -127.f));
    int q3 = (int)rintf(fmaxf(fminf(v[j].w * inv, 127.f), -127.f));
    uint32_t p = (q0 & 255) | ((q1 & 255) << 8) | ((q2 & 255) << 16) | ((q3 & 255) << 24);
    *(uint32_t*)(out + (size_t)o * 4096 + j * 1024 + t * 4) = p;
  }
}

// ===== i8 GEMM, m97 geometry for multi-block occupancy (the TLP experiment) =====
// 128x128 tile, 4 waves (2x2), wave-tile 64x64 -> acc 64 regs; launch_bounds
// (256,4) caps VGPR at 128 (need ~110, safe) -> 4 waves/SIMD -> 2 blocks/CU
// (LDS 64 KiB/block).  BK=128 bytes, double-buffer, ONE {vmcnt(0); barrier}
// per K-tile — exposed drain is hidden by the co-resident block (m114).
// Swizzle (R7/R9-proven for 128-B rows): store chunk c of row r at phys
// c^(r&7); source pre-swizzled (tid&7)^((tid>>3)&7); read phys (ks*4+q)^(l4&7).
__global__ __launch_bounds__(256, 4) void k_gq8(const u8* __restrict__ Ag,
                                                const u8* __restrict__ Bg,
                                                const float* __restrict__ sx,
                                                const float* __restrict__ sw,
                                                float* __restrict__ C,
                                                int M, int N, int K) {
  __shared__ __attribute__((aligned(16))) u8 As[2 * 16384];
  __shared__ __attribute__((aligned(16))) u8 Bs[2 * 16384];
  const int tid  = threadIdx.x;
  const int wave = tid >> 6, lane = tid & 63;
  const int wr = wave >> 1, wc = wave & 1;
  const int m0 = blockIdx.y * 128, n0 = blockIdx.x * 128;
  const int NT = K >> 7;                           // 128-byte K-tiles

  // staging: tile = 128 rows x 128 B = 16 KB = 4 gloads x 256 lanes x 16 B
  const int r0   = tid >> 3;                       // base row 0..31
  const int csrc = (tid & 7) ^ (r0 & 7);           // pre-swizzled source chunk
  const u8* pA = Ag + (size_t)(m0 + r0) * K + csrc * 16;
  const u8* pB = Bg + (size_t)(n0 + r0) * K + csrc * 16;
  const size_t K32 = (size_t)32 * K;
  const int wb = wave << 10;                       // per-wave dest base (1 KB)

#define SA(buf, kt)                                                            \
  do {                                                                         \
    _Pragma("unroll") for (int qq = 0; qq < 4; ++qq)                           \
      gload_lds16(pA + qq * K32 + (kt), As + (buf) * 16384 + qq * 4096 + wb);  \
  } while (0)
#define SB(buf, kt)                                                            \
  do {                                                                         \
    _Pragma("unroll") for (int qq = 0; qq < 4; ++qq)                           \
      gload_lds16(pB + qq * K32 + (kt), Bs + (buf) * 16384 + qq * 4096 + wb);  \
  } while (0)

  // fragment reads: row 128 B; phys chunk = (ks*4 + q) ^ (l4 & 7)
  const int l4 = lane & 15, q = lane >> 4;
  const int ke0 = ((q ^ (l4 & 7)) << 4);           // ks=0 byte offset; ks=1 -> ^64
  const int aoff = ((wr << 6) + l4) << 7;          // (wr*64 + l4) * 128
  const int boff = ((wc << 6) + l4) << 7;

  i32x4 acc[4][4] = {};
  i32x4 ar[4], br[4];

#define LDF(ks)                                                                \
  do {                                                                         \
    const int ko = (ks) ? (ke0 ^ 64) : ke0;                                    \
    const u8* a_ = As + buf * 16384 + aoff;                                    \
    const u8* b_ = Bs + buf * 16384 + boff;                                    \
    _Pragma("unroll") for (int f = 0; f < 4; ++f) {                            \
      ar[f] = *(const i32x4*)(a_ + f * 2048 + ko);                             \
      br[f] = *(const i32x4*)(b_ + f * 2048 + ko);                             \
    }                                                                          \
  } while (0)
#define MFMA16()                                                               \
  do {                                                                         \
    __builtin_amdgcn_s_setprio(1);                                             \
    _Pragma("unroll") for (int i = 0; i < 4; ++i)                              \
      _Pragma("unroll") for (int j = 0; j < 4; ++j)                            \
        acc[i][j] = __builtin_amdgcn_mfma_i32_16x16x64_i8(                     \
            ar[i], br[j], acc[i][j], 0, 0, 0);                                 \
    __builtin_amdgcn_s_setprio(0);                                             \
  } while (0)

  // prologue: stage tile 0 into buf 0
  SA(0, 0);
  SB(0, 0);

  for (int t = 0; t < NT; ++t) {
    const int buf = t & 1, nb = buf ^ 1;
    const int kt1 = (t + 1) << 7;
    const bool st = (t + 1) < NT;

    asm volatile("s_waitcnt vmcnt(0)" ::: "memory");  // tile t landed
    __builtin_amdgcn_s_barrier();                     // collective + WAR for nb

    if (st) { SA(nb, kt1); SB(nb, kt1); }             // stage t+1 (max lead)

    LDF(0);
    MFMA16();
    LDF(1);
    MFMA16();
  }

  // epilogue: C/D col = lane&15, row = (lane>>4)*4 + reg (dtype-independent)
  float swv[4];
#pragma unroll
  for (int j = 0; j < 4; ++j)
    swv[j] = sw[n0 + (wc << 6) + j * 16 + l4];
#pragma unroll
  for (int i = 0; i < 4; ++i) {
    const int row = m0 + (wr << 6) + i * 16 + q * 4;
#pragma unroll
    for (int j = 0; j < 4; ++j) {
      const int col = n0 + (wc << 6) + j * 16 + l4;
#pragma unroll
      for (int v = 0; v < 4; ++v)
        C[(size_t)(row + v) * N + col] = (float)acc[i][j][v] * sx[row + v] * swv[j];
    }
  }
#undef SA
#undef SB
#undef LDF
#undef MFMA16
}

// ---------------- fallback (generic shapes / no workspace): fp32 tiled ----------------
__global__ __launch_bounds__(256) void k_fallback(const float* __restrict__ X,
                                                  const float* __restrict__ W,
                                                  const float* __restrict__ Am,
                                                  const float* __restrict__ Bm,
                                                  float* __restrict__ C,
                                                  int M, int N, int K) {
  __shared__ float Xs[64][16];
  __shared__ float Ws[64][17];
  const int tid = threadIdx.x;
  const int tn = tid & 15, tm = tid >> 4;
  const int m0 = blockIdx.y * 64, n0 = blockIdx.x * 64;
  float acc[4][4] = {};
  for (int kt = 0; kt < K; kt += 16) {
    __syncthreads();
#pragma unroll
    for (int qq = 0; qq < 4; ++qq) {
      int idx = qq * 256 + tid;
      int r = idx >> 4, c = idx & 15;
      Xs[r][c] = X[(size_t)(m0 + r) * K + kt + c];
      float w = W[(size_t)(n0 + r) * K + kt + c];
      float4 b = *(const float4*)(Bm + ((n0 + r) << 2));
      w += 4.f * (b.x * Am[kt + c] + b.y * Am[4096 + kt + c] +
                  b.z * Am[8192 + kt + c] + b.w * Am[12288 + kt + c]);
      Ws[r][c] = w;
    }
    __syncthreads();
#pragma unroll
    for (int k = 0; k < 16; ++k) {
      float xv[4], wv[4];
#pragma unroll
      for (int i = 0; i < 4; ++i) xv[i] = Xs[tm * 4 + i][k];
#pragma unroll
      for (int j = 0; j < 4; ++j) wv[j] = Ws[tn * 4 + j][k];
#pragma unroll
      for (int i = 0; i < 4; ++i)
#pragma unroll
        for (int j = 0; j < 4; ++j) acc[i][j] += xv[i] * wv[j];
    }
  }
#pragma unroll
  for (int i = 0; i < 4; ++i)
#pragma unroll
    for (int j = 0; j < 4; ++j)
      C[(size_t)(m0 + tm * 4 + i) * N + n0 + tn * 4 + j] = acc[i][j];
}

extern "C" void kernel_launch(void* const* d_in, const int* in_sizes, int n_in,
                              void* d_out, int out_size, void* d_ws, size_t ws_size,
                              hipStream_t stream) {
  const float* x  = (const float*)d_in[0];
  const float* W  = (const float*)d_in[1];
  const float* lA = (const float*)d_in[2];
  const float* lB = (const float*)d_in[3];
  float* out = (float*)d_out;
  const int K = 4096, N = 4096;
  const int M = in_sizes[0] / K;   // 8192
  const size_t need = (size_t)(M + N) * K + (size_t)(M + N) * sizeof(float);

  if (ws_size >= need && (M % 128) == 0) {
    i8* xb = (i8*)d_ws;
    i8* wb = xb + (size_t)M * K;
    float* sx = (float*)(wb + (size_t)N * K);
    float* sw = sx + M;
    k_quant_x<<<dim3(M), dim3(256), 0, stream>>>(x, xb, sx);
    k_quant_w<<<dim3(N), dim3(256), 0, stream>>>(W, lA, lB, wb, sw);
    k_gq8<<<dim3(N / 128, M / 128), dim3(256), 0, stream>>>(
        (const u8*)xb, (const u8*)wb, sx, sw, out, M, N, K);
  } else {
    k_fallback<<<dim3(N / 64, M / 64), dim3(256), 0, stream>>>(x, W, lA, lB, out, M, N, K);
  }
}

// Round 13
// 209.995 us; speedup vs baseline: 1.0113x; 1.0113x over previous
//
#include <hip/hip_runtime.h>
#include <stdint.h>

typedef signed char i8;
typedef unsigned char u8;
typedef __attribute__((ext_vector_type(4))) int i32x4;
typedef __attribute__((ext_vector_type(4))) uint32_t u32x4;

// Packed fragment layout (A and B identical): element (row, k) ->
//   r16 = row>>4, l4 = row&15, t = k>>7, ks = (k>>6)&1, q = (k>>4)&3, b = k&15
//   byte addr = ((r16*NT + t)*2 + ks)*1024 + (q*16 + l4)*16 + b
// One (r16, t, ks) chunk = 1 KB read by a wave as lane*16 contiguous.

// ---------- quant+pack x: block = 16 rows, 1024 threads (wave w = row w) ----------
__global__ __launch_bounds__(1024) void k_qx(const float* __restrict__ in,
                                             u8* __restrict__ out,
                                             float* __restrict__ scale, int NT) {
  __shared__ u8 lds[16][4096];
  const int w = threadIdx.x >> 6, lane = threadIdx.x & 63;
  const int r16 = blockIdx.x;
  const int row = r16 * 16 + w;
  const float4* src = (const float4*)(in + (size_t)row * 4096);
  float4 v[16];
  float m = 0.f;
#pragma unroll
  for (int j = 0; j < 16; ++j) {
    v[j] = src[j * 64 + lane];
    m = fmaxf(m, fmaxf(fmaxf(fabsf(v[j].x), fabsf(v[j].y)),
                       fmaxf(fabsf(v[j].z), fabsf(v[j].w))));
  }
#pragma unroll
  for (int off = 32; off; off >>= 1) m = fmaxf(m, __shfl_xor(m, off));
  const float inv = m > 0.f ? 127.f / m : 0.f;
  if (lane == 0) scale[row] = m / 127.f;
  uint32_t* lrow = (uint32_t*)&lds[w][0];
#pragma unroll
  for (int j = 0; j < 16; ++j) {
    int q0 = (int)rintf(fmaxf(fminf(v[j].x * inv, 127.f), -127.f));
    int q1 = (int)rintf(fmaxf(fminf(v[j].y * inv, 127.f), -127.f));
    int q2 = (int)rintf(fmaxf(fminf(v[j].z * inv, 127.f), -127.f));
    int q3 = (int)rintf(fmaxf(fminf(v[j].w * inv, 127.f), -127.f));
    lrow[j * 64 + lane] = (q0 & 255) | ((q1 & 255) << 8) | ((q2 & 255) << 16) | ((q3 & 255) << 24);
  }
  __syncthreads();
  // packed write-out: thread writes 64 B contiguous (4 chunks of 16 B)
  u8* dst = out + (size_t)r16 * ((size_t)NT * 2048) + (size_t)threadIdx.x * 64;
#pragma unroll
  for (int cc = 0; cc < 4; ++cc) {
    int c = threadIdx.x * 4 + cc;
    int ls = c & 63, ks = (c >> 6) & 1, tt = c >> 7;
    int q = ls >> 4, l4 = ls & 15;
    u32x4 d = *(const u32x4*)&lds[l4][tt * 128 + ks * 64 + q * 16];
    *(u32x4*)(dst + cc * 16) = d;
  }
}

// ---------- quant+pack W' = W + 4*B@A: same structure + fold ----------
__global__ __launch_bounds__(1024) void k_qw(const float* __restrict__ W,
                                             const float* __restrict__ Am,
                                             const float* __restrict__ Bm,
                                             u8* __restrict__ out,
                                             float* __restrict__ scale, int NT) {
  __shared__ u8 lds[16][4096];
  const int w = threadIdx.x >> 6, lane = threadIdx.x & 63;
  const int r16 = blockIdx.x;
  const int o = r16 * 16 + w;
  const float4 b4 = *(const float4*)(Bm + (o << 2));
  const float4* wsrc = (const float4*)(W + (size_t)o * 4096);
  const float4* a0p = (const float4*)(Am);
  const float4* a1p = (const float4*)(Am + 4096);
  const float4* a2p = (const float4*)(Am + 8192);
  const float4* a3p = (const float4*)(Am + 12288);
  float4 v[16];
  float m = 0.f;
#pragma unroll
  for (int j = 0; j < 16; ++j) {
    const int idx = j * 64 + lane;
    float4 wv = wsrc[idx];
    float4 a0 = a0p[idx], a1 = a1p[idx], a2 = a2p[idx], a3 = a3p[idx];
    wv.x += 4.f * (b4.x * a0.x + b4.y * a1.x + b4.z * a2.x + b4.w * a3.x);
    wv.y += 4.f * (b4.x * a0.y + b4.y * a1.y + b4.z * a2.y + b4.w * a3.y);
    wv.z += 4.f * (b4.x * a0.z + b4.y * a1.z + b4.z * a2.z + b4.w * a3.z);
    wv.w += 4.f * (b4.x * a0.w + b4.y * a1.w + b4.z * a2.w + b4.w * a3.w);
    v[j] = wv;
    m = fmaxf(m, fmaxf(fmaxf(fabsf(wv.x), fabsf(wv.y)), fmaxf(fabsf(wv.z), fabsf(wv.w))));
  }
#pragma unroll
  for (int off = 32; off; off >>= 1) m = fmaxf(m, __shfl_xor(m, off));
  const float inv = m > 0.f ? 127.f / m : 0.f;
  if (lane == 0) scale[o] = m / 127.f;
  uint32_t* lrow = (uint32_t*)&lds[w][0];
#pragma unroll
  for (int j = 0; j < 16; ++j) {
    int q0 = (int)rintf(fmaxf(fminf(v[j].x * inv, 127.f), -127.f));
    int q1 = (int)rintf(fmaxf(fminf(v[j].y * inv, 127.f), -127.f));
    int q2 = (int)rintf(fmaxf(fminf(v[j].z * inv, 127.f), -127.f));
    int q3 = (int)rintf(fmaxf(fminf(v[j].w * inv, 127.f), -127.f));
    lrow[j * 64 + lane] = (q0 & 255) | ((q1 & 255) << 8) | ((q2 & 255) << 16) | ((q3 & 255) << 24);
  }
  __syncthreads();
  u8* dst = out + (size_t)r16 * ((size_t)NT * 2048) + (size_t)threadIdx.x * 64;
#pragma unroll
  for (int cc = 0; cc < 4; ++cc) {
    int c = threadIdx.x * 4 + cc;
    int ls = c & 63, ks = (c >> 6) & 1, tt = c >> 7;
    int q = ls >> 4, l4 = ls & 15;
    u32x4 d = *(const u32x4*)&lds[l4][tt * 128 + ks * 64 + q * 16];
    *(u32x4*)(dst + cc * 16) = d;
  }
}

// ===== no-LDS, no-barrier i8 GEMM from packed fragments =====
// Wave-tile 128x64. Per k-half (64 elems): 8 A-frags + 4 B-frags = 12 coalesced
// global_load_dwordx4 (L2-served), ping-pong double-buffered in registers with
// counted vmcnt(12); 32 MFMA per half. No __shared__, no s_barrier in the loop.
// XCD-banded mapping: xcd = bid&7 owns mw-band (A-band = 4 MB = one L2).
// Requires N == 4096 (nw = lw & 63).
__global__ __launch_bounds__(256, 2) void k_gpk(const u8* __restrict__ Ap,
                                                const u8* __restrict__ Bp,
                                                const float* __restrict__ sx,
                                                const float* __restrict__ sw,
                                                float* __restrict__ C,
                                                int M, int N, int K) {
  const int tid = threadIdx.x;
  const int lane = tid & 63;
  const int wv = __builtin_amdgcn_readfirstlane(tid >> 6);
  const int NT = K >> 7;
  const int mpx = (M >> 7) >> 3;                 // mw per xcd band
  const int bid = blockIdx.x;
  const int xcd = bid & 7;
  const int lw = (bid >> 3) * 4 + wv;            // local wave id within band
  const int nw = lw & 63;                        // N/64 == 64
  const int mw = xcd * mpx + (lw >> 6);
  const size_t RS = (size_t)NT << 11;            // bytes per r16 block
  const u8* pa = Ap + (size_t)(mw * 8) * RS;
  const u8* pb = Bp + (size_t)(nw * 4) * RS;
  const int vbase = lane << 4;

  i32x4 acc[8][4] = {};
  i32x4 a0[8], b0[4], a1[8], b1[4];

#define LOADH(AA, BB, h)                                                       \
  do {                                                                         \
    const int off_ = ((h) << 10) + vbase;                                      \
    _Pragma("unroll") for (int f = 0; f < 8; ++f)                              \
      AA[f] = *(const i32x4*)(pa + f * RS + off_);                             \
    _Pragma("unroll") for (int g = 0; g < 4; ++g)                              \
      BB[g] = *(const i32x4*)(pb + g * RS + off_);                             \
  } while (0)
#define MFMAH(AA, BB)                                                          \
  do {                                                                         \
    __builtin_amdgcn_s_setprio(1);                                             \
    _Pragma("unroll") for (int f = 0; f < 8; ++f)                              \
      _Pragma("unroll") for (int g = 0; g < 4; ++g)                            \
        acc[f][g] = __builtin_amdgcn_mfma_i32_16x16x64_i8(AA[f], BB[g],        \
                                                          acc[f][g], 0, 0, 0); \
    __builtin_amdgcn_s_setprio(0);                                             \
  } while (0)

  const int NH = NT * 2;                         // 64 k-halves
  LOADH(a0, b0, 0);
  for (int h = 0; h < NH; h += 2) {
    if (h + 1 < NH) {
      LOADH(a1, b1, h + 1);
      asm volatile("s_waitcnt vmcnt(12)" ::: "memory");   // half h landed
    } else {
      asm volatile("s_waitcnt vmcnt(0)" ::: "memory");
    }
    MFMAH(a0, b0);
    if (h + 2 < NH) {
      LOADH(a0, b0, h + 2);
      asm volatile("s_waitcnt vmcnt(12)" ::: "memory");   // half h+1 landed
    } else {
      asm volatile("s_waitcnt vmcnt(0)" ::: "memory");
    }
    MFMAH(a1, b1);
  }

  // epilogue: C/D col = lane&15, row = (lane>>4)*4 + reg (dtype-independent)
  const int q = lane >> 4, l4 = lane & 15;
  float swv[4];
#pragma unroll
  for (int g = 0; g < 4; ++g) swv[g] = sw[nw * 64 + g * 16 + l4];
#pragma unroll
  for (int f = 0; f < 8; ++f) {
    const int row = mw * 128 + f * 16 + q * 4;
#pragma unroll
    for (int g = 0; g < 4; ++g) {
      const int col = nw * 64 + g * 16 + l4;
#pragma unroll
      for (int v = 0; v < 4; ++v)
        C[(size_t)(row + v) * N + col] = (float)acc[f][g][v] * sx[row + v] * swv[g];
    }
  }
#undef LOADH
#undef MFMAH
}

// ---------------- fallback (generic shapes / no workspace): fp32 tiled ----------------
__global__ __launch_bounds__(256) void k_fallback(const float* __restrict__ X,
                                                  const float* __restrict__ W,
                                                  const float* __restrict__ Am,
                                                  const float* __restrict__ Bm,
                                                  float* __restrict__ C,
                                                  int M, int N, int K) {
  __shared__ float Xs[64][16];
  __shared__ float Ws[64][17];
  const int tid = threadIdx.x;
  const int tn = tid & 15, tm = tid >> 4;
  const int m0 = blockIdx.y * 64, n0 = blockIdx.x * 64;
  float acc[4][4] = {};
  for (int kt = 0; kt < K; kt += 16) {
    __syncthreads();
#pragma unroll
    for (int qq = 0; qq < 4; ++qq) {
      int idx = qq * 256 + tid;
      int r = idx >> 4, c = idx & 15;
      Xs[r][c] = X[(size_t)(m0 + r) * K + kt + c];
      float w = W[(size_t)(n0 + r) * K + kt + c];
      float4 b = *(const float4*)(Bm + ((n0 + r) << 2));
      w += 4.f * (b.x * Am[kt + c] + b.y * Am[4096 + kt + c] +
                  b.z * Am[8192 + kt + c] + b.w * Am[12288 + kt + c]);
      Ws[r][c] = w;
    }
    __syncthreads();
#pragma unroll
    for (int k = 0; k < 16; ++k) {
      float xv[4], wv[4];
#pragma unroll
      for (int i = 0; i < 4; ++i) xv[i] = Xs[tm * 4 + i][k];
#pragma unroll
      for (int j = 0; j < 4; ++j) wv[j] = Ws[tn * 4 + j][k];
#pragma unroll
      for (int i = 0; i < 4; ++i)
#pragma unroll
        for (int j = 0; j < 4; ++j) acc[i][j] += xv[i] * wv[j];
    }
  }
#pragma unroll
  for (int i = 0; i < 4; ++i)
#pragma unroll
    for (int j = 0; j < 4; ++j)
      C[(size_t)(m0 + tm * 4 + i) * N + n0 + tn * 4 + j] = acc[i][j];
}

extern "C" void kernel_launch(void* const* d_in, const int* in_sizes, int n_in,
                              void* d_out, int out_size, void* d_ws, size_t ws_size,
                              hipStream_t stream) {
  const float* x  = (const float*)d_in[0];
  const float* W  = (const float*)d_in[1];
  const float* lA = (const float*)d_in[2];
  const float* lB = (const float*)d_in[3];
  float* out = (float*)d_out;
  const int K = 4096, N = 4096;
  const int M = in_sizes[0] / K;   // 8192
  const int NT = K >> 7;           // 32
  const size_t need = (size_t)(M + N) * K + (size_t)(M + N) * sizeof(float);

  if (ws_size >= need && N == 4096 && (M % 1024) == 0) {
    u8* xb = (u8*)d_ws;
    u8* wb = xb + (size_t)M * K;
    float* sx = (float*)(wb + (size_t)N * K);
    float* sw = sx + M;
    k_qx<<<dim3(M / 16), dim3(1024), 0, stream>>>(x, xb, sx, NT);
    k_qw<<<dim3(N / 16), dim3(1024), 0, stream>>>(W, lA, lB, wb, sw, NT);
    const int nblocks = (M >> 7) * (N >> 6) / 4;   // waves/4
    k_gpk<<<dim3(nblocks), dim3(256), 0, stream>>>(xb, wb, sx, sw, out, M, N, K);
  } else {
    k_fallback<<<dim3(N / 64, M / 64), dim3(256), 0, stream>>>(x, W, lA, lB, out, M, N, K);
  }
}

// Round 14
// 192.725 us; speedup vs baseline: 1.1020x; 1.0896x over previous
//
#include <hip/hip_runtime.h>
#include <stdint.h>

typedef signed char i8;
typedef unsigned char u8;
typedef __attribute__((ext_vector_type(4))) int i32x4;

__device__ __forceinline__ void gload_lds16(const void* g, void* l) {
  __builtin_amdgcn_global_load_lds(
      (__attribute__((address_space(1))) void*)const_cast<void*>(g),
      (__attribute__((address_space(3))) void*)l, 16, 0, 0);
}

// ---------- fused prep: one grid quantizes both x (rows) and W' (rows) ----------
// bid < M: row of x.  bid >= M: row o = bid - M of W' = W + 4*B@A.
// Per-row absmax -> i8 + f32 scale.  256 threads/row.
__global__ __launch_bounds__(256) void k_quant(const float* __restrict__ x,
                                               const float* __restrict__ W,
                                               const float* __restrict__ Am,
                                               const float* __restrict__ Bm,
                                               i8* __restrict__ xq,
                                               i8* __restrict__ wq,
                                               float* __restrict__ sx,
                                               float* __restrict__ sw, int M) {
  const int bid = blockIdx.x, t = threadIdx.x;
  const bool isx = bid < M;
  const int row = isx ? bid : bid - M;
  float4 v[4];
  float m = 0.f;
  if (isx) {
    const float4* src = (const float4*)(x + (size_t)row * 4096);
#pragma unroll
    for (int j = 0; j < 4; ++j) {
      v[j] = src[j * 256 + t];
      m = fmaxf(m, fmaxf(fmaxf(fabsf(v[j].x), fabsf(v[j].y)),
                         fmaxf(fabsf(v[j].z), fabsf(v[j].w))));
    }
  } else {
    const float4 b4 = *(const float4*)(Bm + (row << 2));
#pragma unroll
    for (int j = 0; j < 4; ++j) {
      const int i = (j * 256 + t) * 4;
      float4 w  = *(const float4*)(W + ((size_t)row << 12) + i);
      float4 a0 = *(const float4*)(Am + i);
      float4 a1 = *(const float4*)(Am + 4096 + i);
      float4 a2 = *(const float4*)(Am + 8192 + i);
      float4 a3 = *(const float4*)(Am + 12288 + i);
      w.x += 4.f * (b4.x * a0.x + b4.y * a1.x + b4.z * a2.x + b4.w * a3.x);
      w.y += 4.f * (b4.x * a0.y + b4.y * a1.y + b4.z * a2.y + b4.w * a3.y);
      w.z += 4.f * (b4.x * a0.z + b4.y * a1.z + b4.z * a2.z + b4.w * a3.z);
      w.w += 4.f * (b4.x * a0.w + b4.y * a1.w + b4.z * a2.w + b4.w * a3.w);
      v[j] = w;
      m = fmaxf(m, fmaxf(fmaxf(fabsf(w.x), fabsf(w.y)), fmaxf(fabsf(w.z), fabsf(w.w))));
    }
  }
#pragma unroll
  for (int off = 32; off; off >>= 1) m = fmaxf(m, __shfl_xor(m, off));
  __shared__ float wmax[4];
  if ((t & 63) == 0) wmax[t >> 6] = m;
  __syncthreads();
  m = fmaxf(fmaxf(wmax[0], wmax[1]), fmaxf(wmax[2], wmax[3]));
  const float inv = m > 0.f ? 127.f / m : 0.f;
  if (t == 0) { if (isx) sx[row] = m / 127.f; else sw[row] = m / 127.f; }
  i8* out = isx ? xq : wq;
#pragma unroll
  for (int j = 0; j < 4; ++j) {
    int q0 = (int)rintf(fmaxf(fminf(v[j].x * inv, 127.f), -127.f));
    int q1 = (int)rintf(fmaxf(fminf(v[j].y * inv, 127.f), -127.f));
    int q2 = (int)rintf(fmaxf(fminf(v[j].z * inv, 127.f), -127.f));
    int q3 = (int)rintf(fmaxf(fminf(v[j].w * inv, 127.f), -127.f));
    uint32_t p = (q0 & 255) | ((q1 & 255) << 8) | ((q2 & 255) << 16) | ((q3 & 255) << 24);
    *(uint32_t*)(out + (size_t)row * 4096 + (j * 256 + t) * 4) = p;
  }
}

// ===== i8 GEMM (R9 structure verbatim) + T1 bijective XCD swizzle =====
// C[m][n] = sx[m]*sw[n] * sum_k Aq[m][k]*Bq[n][k].  256x256 tile, 8 waves
// (interleaved mapping), quadrant phases, double-buffered LDS (128 KiB),
// counted vmcnt(4) chain (never 0 in loop), XOR swizzle (0 conflicts, measured).
__global__ __launch_bounds__(512, 2) void k_gq8(const u8* __restrict__ Ag,
                                                const u8* __restrict__ Bg,
                                                const float* __restrict__ sx,
                                                const float* __restrict__ sw,
                                                float* __restrict__ C,
                                                int M, int N, int K) {
  __shared__ __attribute__((aligned(16))) u8 As[2 * 32768];
  __shared__ __attribute__((aligned(16))) u8 Bs[2 * 32768];
  const int tid  = threadIdx.x;
  const int wave = tid >> 6, lane = tid & 63;
  const int wr = wave >> 2, wc = wave & 3;
  const int NT = K >> 7;                           // 128-byte K-tiles

  // T1 bijective XCD swizzle (launch guard ensures nwg % 8 == 0)
  const int gx = gridDim.x;
  const int nwg = gx * gridDim.y;
  const int orig = blockIdx.y * gx + blockIdx.x;
  const int swz = (orig & 7) * (nwg >> 3) + (orig >> 3);
  const int m0 = (swz / gx) * 256;
  const int n0 = (swz % gx) * 256;

  // staging: unit = 64 rows x 128 B = 8 KB = 512 lanes x 16B (1 gload)
  const int srow = tid >> 3;                       // 0..63
  const int csrc = (tid & 7) ^ (srow & 7);         // pre-swizzled source chunk
  const u8* pA = Ag + (size_t)(m0 + srow) * K + csrc * 16;
  const u8* pB = Bg + (size_t)(n0 + srow) * K + csrc * 16;
  const size_t KH = (size_t)128 * K;               // half stride
  const size_t KU = (size_t)64 * K;                // unit stride
  const int wb = wave << 10;                       // wave-uniform LDS base (bytes)

#define SA(nb, h, kt)                                                          \
  do {                                                                         \
    gload_lds16(pA + (h) * KH + (kt),      As + (nb) * 32768 + (h) * 16384 + wb);       \
    gload_lds16(pA + (h) * KH + KU + (kt), As + (nb) * 32768 + (h) * 16384 + 8192 + wb);\
  } while (0)
#define SB(nb, h, kt)                                                          \
  do {                                                                         \
    gload_lds16(pB + (h) * KH + (kt),      Bs + (nb) * 32768 + (h) * 16384 + wb);       \
    gload_lds16(pB + (h) * KH + KU + (kt), Bs + (nb) * 32768 + (h) * 16384 + 8192 + wb);\
  } while (0)

  // fragment reads: row 128 B; phys chunk = (ks*4 + q) ^ (lane&7)
  const int l4 = lane & 15, q = lane >> 4, l7 = lane & 7;
  const int ke0 = (q ^ l7) << 4;                   // bytes; ks=1 -> ke0 ^ 64
  const int aoff = ((wr << 6) + l4) << 7;          // (wr*64 + l4)*128
  const int boff = ((wc << 5) + l4) << 7;          // (wc*32 + l4)*128

  i32x4 acc[8][4] = {};
  i32x4 ar[4][2];      // current A-half [f][ks]
  i32x4 bq[2][2][2];   // both B-halves [nh][g][ks]

#define LDA(buf, mh)                                                           \
  do {                                                                         \
    const u8* b_ = As + (buf) * 32768 + (mh) * 16384 + aoff;                   \
    _Pragma("unroll") for (int f = 0; f < 4; ++f) {                            \
      ar[f][0] = *(const i32x4*)(b_ + f * 2048 + ke0);                         \
      ar[f][1] = *(const i32x4*)(b_ + f * 2048 + (ke0 ^ 64));                  \
    }                                                                          \
  } while (0)
#define LDB(buf, nh)                                                           \
  do {                                                                         \
    const u8* b_ = Bs + (buf) * 32768 + (nh) * 16384 + boff;                   \
    _Pragma("unroll") for (int g = 0; g < 2; ++g) {                            \
      bq[nh][g][0] = *(const i32x4*)(b_ + g * 2048 + ke0);                     \
      bq[nh][g][1] = *(const i32x4*)(b_ + g * 2048 + (ke0 ^ 64));              \
    }                                                                          \
  } while (0)
#define MFMA16(mh, nh)                                                         \
  do {                                                                         \
    __builtin_amdgcn_s_setprio(1);                                             \
    _Pragma("unroll") for (int f = 0; f < 4; ++f)                              \
      _Pragma("unroll") for (int g = 0; g < 2; ++g)                            \
        _Pragma("unroll") for (int ks = 0; ks < 2; ++ks)                       \
          acc[(mh) * 4 + f][(nh) * 2 + g] =                                    \
              __builtin_amdgcn_mfma_i32_16x16x64_i8(                           \
                  ar[f][ks], bq[nh][g][ks], acc[(mh) * 4 + f][(nh) * 2 + g],   \
                  0, 0, 0);                                                    \
    __builtin_amdgcn_s_setprio(0);                                             \
  } while (0)

  // prologue: stage tile 0 in consumption order A0,B0,B1,A1
  SA(0, 0, 0);
  SB(0, 0, 0);
  SB(0, 1, 0);
  SA(0, 1, 0);
  asm volatile("s_waitcnt vmcnt(4)" ::: "memory");   // A0,B0 landed
  __builtin_amdgcn_s_barrier();

  for (int t = 0; t < NT; ++t) {
    const int buf = t & 1, nb = buf ^ 1;
    const int kt1 = (t + 1) << 7;
    const bool st = (t + 1) < NT;

    // ---- ph1: quadrant (0,0); reads A0(8)+B0(4); stages A0(t+1) ----
    LDA(buf, 0);
    LDB(buf, 0);
    if (st) SA(nb, 0, kt1);
    asm volatile("s_waitcnt lgkmcnt(8)" ::: "memory");
    __builtin_amdgcn_s_barrier();
    asm volatile("s_waitcnt lgkmcnt(0)" ::: "memory");
    MFMA16(0, 0);
    if (st) { asm volatile("s_waitcnt vmcnt(4)" ::: "memory"); }
    else    { asm volatile("s_waitcnt vmcnt(2)" ::: "memory"); }
    __builtin_amdgcn_s_barrier();

    // ---- ph2: quadrant (0,1); reads B1(4); stages B0(t+1) ----
    LDB(buf, 1);
    if (st) SB(nb, 0, kt1);
    __builtin_amdgcn_s_barrier();
    asm volatile("s_waitcnt lgkmcnt(0)" ::: "memory");
    MFMA16(0, 1);
    if (st) { asm volatile("s_waitcnt vmcnt(4)" ::: "memory"); }
    else    { asm volatile("s_waitcnt vmcnt(0)" ::: "memory"); }
    __builtin_amdgcn_s_barrier();

    // ---- ph3: quadrant (1,1); reads A1(8); stages B1(t+1) ----
    LDA(buf, 1);
    if (st) SB(nb, 1, kt1);
    __builtin_amdgcn_s_barrier();
    asm volatile("s_waitcnt lgkmcnt(0)" ::: "memory");
    MFMA16(1, 1);
    __builtin_amdgcn_s_barrier();

    // ---- ph4: quadrant (1,0); no reads; stages A1(t+1) ----
    if (st) SA(nb, 1, kt1);
    __builtin_amdgcn_s_barrier();
    MFMA16(1, 0);
    if (st) { asm volatile("s_waitcnt vmcnt(4)" ::: "memory"); }
    __builtin_amdgcn_s_barrier();
  }

  // epilogue: C/D col = lane&15, row = (lane>>4)*4 + reg (dtype-independent)
  float swv[4];
#pragma unroll
  for (int j = 0; j < 4; ++j)
    swv[j] = sw[n0 + (j >> 1) * 128 + wc * 32 + (j & 1) * 16 + l4];
#pragma unroll
  for (int i = 0; i < 8; ++i) {
    const int mh = i >> 2, f = i & 3;
    const int row = m0 + mh * 128 + wr * 64 + f * 16 + q * 4;
#pragma unroll
    for (int j = 0; j < 4; ++j) {
      const int nh = j >> 1, g = j & 1;
      const int col = n0 + nh * 128 + wc * 32 + g * 16 + l4;
#pragma unroll
      for (int v = 0; v < 4; ++v)
        C[(size_t)(row + v) * N + col] = (float)acc[i][j][v] * sx[row + v] * swv[j];
    }
  }
#undef SA
#undef SB
#undef LDA
#undef LDB
#undef MFMA16
}

// ---------------- fallback (generic shapes / no workspace): fp32 tiled ----------------
__global__ __launch_bounds__(256) void k_fallback(const float* __restrict__ X,
                                                  const float* __restrict__ W,
                                                  const float* __restrict__ Am,
                                                  const float* __restrict__ Bm,
                                                  float* __restrict__ C,
                                                  int M, int N, int K) {
  __shared__ float Xs[64][16];
  __shared__ float Ws[64][17];
  const int tid = threadIdx.x;
  const int tn = tid & 15, tm = tid >> 4;
  const int m0 = blockIdx.y * 64, n0 = blockIdx.x * 64;
  float acc[4][4] = {};
  for (int kt = 0; kt < K; kt += 16) {
    __syncthreads();
#pragma unroll
    for (int qq = 0; qq < 4; ++qq) {
      int idx = qq * 256 + tid;
      int r = idx >> 4, c = idx & 15;
      Xs[r][c] = X[(size_t)(m0 + r) * K + kt + c];
      float w = W[(size_t)(n0 + r) * K + kt + c];
      float4 b = *(const float4*)(Bm + ((n0 + r) << 2));
      w += 4.f * (b.x * Am[kt + c] + b.y * Am[4096 + kt + c] +
                  b.z * Am[8192 + kt + c] + b.w * Am[12288 + kt + c]);
      Ws[r][c] = w;
    }
    __syncthreads();
#pragma unroll
    for (int k = 0; k < 16; ++k) {
      float xv[4], wv[4];
#pragma unroll
      for (int i = 0; i < 4; ++i) xv[i] = Xs[tm * 4 + i][k];
#pragma unroll
      for (int j = 0; j < 4; ++j) wv[j] = Ws[tn * 4 + j][k];
#pragma unroll
      for (int i = 0; i < 4; ++i)
#pragma unroll
        for (int j = 0; j < 4; ++j) acc[i][j] += xv[i] * wv[j];
    }
  }
#pragma unroll
  for (int i = 0; i < 4; ++i)
#pragma unroll
    for (int j = 0; j < 4; ++j)
      C[(size_t)(m0 + tm * 4 + i) * N + n0 + tn * 4 + j] = acc[i][j];
}

extern "C" void kernel_launch(void* const* d_in, const int* in_sizes, int n_in,
                              void* d_out, int out_size, void* d_ws, size_t ws_size,
                              hipStream_t stream) {
  const float* x  = (const float*)d_in[0];
  const float* W  = (const float*)d_in[1];
  const float* lA = (const float*)d_in[2];
  const float* lB = (const float*)d_in[3];
  float* out = (float*)d_out;
  const int K = 4096, N = 4096;
  const int M = in_sizes[0] / K;   // 8192
  const size_t need = (size_t)(M + N) * K + (size_t)(M + N) * sizeof(float);
  const int nwg = (N / 256) * (M / 256);

  if (ws_size >= need && (M % 256) == 0 && (nwg % 8) == 0) {
    i8* xb = (i8*)d_ws;
    i8* wb = xb + (size_t)M * K;
    float* sx = (float*)(wb + (size_t)N * K);
    float* sw = sx + M;
    k_quant<<<dim3(M + N), dim3(256), 0, stream>>>(x, W, lA, lB, xb, wb, sx, sw, M);
    k_gq8<<<dim3(N / 256, M / 256), dim3(512), 0, stream>>>(
        (const u8*)xb, (const u8*)wb, sx, sw, out, M, N, K);
  } else {
    k_fallback<<<dim3(N / 64, M / 64), dim3(256), 0, stream>>>(x, W, lA, lB, out, M, N, K);
  }
}

// Round 15
// 191.716 us; speedup vs baseline: 1.1078x; 1.0053x over previous
//
#include <hip/hip_runtime.h>
#include <stdint.h>

typedef signed char i8;
typedef unsigned char u8;
typedef __attribute__((ext_vector_type(4))) int i32x4;

__device__ __forceinline__ void gload_lds16(const void* g, void* l) {
  __builtin_amdgcn_global_load_lds(
      (__attribute__((address_space(1))) void*)const_cast<void*>(g),
      (__attribute__((address_space(3))) void*)l, 16, 0, 0);
}

// ---------- fused prep: one grid quantizes both x (rows) and W' (rows) ----------
// bid < M: row of x.  bid >= M: row o = bid - M of W' = W + 4*B@A.
// Per-row absmax -> i8 + f32 scale.  256 threads/row.
__global__ __launch_bounds__(256) void k_quant(const float* __restrict__ x,
                                               const float* __restrict__ W,
                                               const float* __restrict__ Am,
                                               const float* __restrict__ Bm,
                                               i8* __restrict__ xq,
                                               i8* __restrict__ wq,
                                               float* __restrict__ sx,
                                               float* __restrict__ sw, int M) {
  const int bid = blockIdx.x, t = threadIdx.x;
  const bool isx = bid < M;
  const int row = isx ? bid : bid - M;
  float4 v[4];
  float m = 0.f;
  if (isx) {
    const float4* src = (const float4*)(x + (size_t)row * 4096);
#pragma unroll
    for (int j = 0; j < 4; ++j) {
      v[j] = src[j * 256 + t];
      m = fmaxf(m, fmaxf(fmaxf(fabsf(v[j].x), fabsf(v[j].y)),
                         fmaxf(fabsf(v[j].z), fabsf(v[j].w))));
    }
  } else {
    const float4 b4 = *(const float4*)(Bm + (row << 2));
#pragma unroll
    for (int j = 0; j < 4; ++j) {
      const int i = (j * 256 + t) * 4;
      float4 w  = *(const float4*)(W + ((size_t)row << 12) + i);
      float4 a0 = *(const float4*)(Am + i);
      float4 a1 = *(const float4*)(Am + 4096 + i);
      float4 a2 = *(const float4*)(Am + 8192 + i);
      float4 a3 = *(const float4*)(Am + 12288 + i);
      w.x += 4.f * (b4.x * a0.x + b4.y * a1.x + b4.z * a2.x + b4.w * a3.x);
      w.y += 4.f * (b4.x * a0.y + b4.y * a1.y + b4.z * a2.y + b4.w * a3.y);
      w.z += 4.f * (b4.x * a0.z + b4.y * a1.z + b4.z * a2.z + b4.w * a3.z);
      w.w += 4.f * (b4.x * a0.w + b4.y * a1.w + b4.z * a2.w + b4.w * a3.w);
      v[j] = w;
      m = fmaxf(m, fmaxf(fmaxf(fabsf(w.x), fabsf(w.y)), fmaxf(fabsf(w.z), fabsf(w.w))));
    }
  }
#pragma unroll
  for (int off = 32; off; off >>= 1) m = fmaxf(m, __shfl_xor(m, off));
  __shared__ float wmax[4];
  if ((t & 63) == 0) wmax[t >> 6] = m;
  __syncthreads();
  m = fmaxf(fmaxf(wmax[0], wmax[1]), fmaxf(wmax[2], wmax[3]));
  const float inv = m > 0.f ? 127.f / m : 0.f;
  if (t == 0) { if (isx) sx[row] = m / 127.f; else sw[row] = m / 127.f; }
  i8* out = isx ? xq : wq;
#pragma unroll
  for (int j = 0; j < 4; ++j) {
    int q0 = (int)rintf(fmaxf(fminf(v[j].x * inv, 127.f), -127.f));
    int q1 = (int)rintf(fmaxf(fminf(v[j].y * inv, 127.f), -127.f));
    int q2 = (int)rintf(fmaxf(fminf(v[j].z * inv, 127.f), -127.f));
    int q3 = (int)rintf(fmaxf(fminf(v[j].w * inv, 127.f), -127.f));
    uint32_t p = (q0 & 255) | ((q1 & 255) << 8) | ((q2 & 255) << 16) | ((q3 & 255) << 24);
    *(uint32_t*)(out + (size_t)row * 4096 + (j * 256 + t) * 4) = p;
  }
}

// ===== i8 GEMM — R9 structure verbatim (measured-best 143 us, no XCD swizzle) =====
// C[m][n] = sx[m]*sw[n] * sum_k Aq[m][k]*Bq[n][k].  256x256 tile, 8 waves
// (interleaved mapping), quadrant phases, double-buffered LDS (128 KiB),
// counted vmcnt(4) chain (never 0 in loop), XOR swizzle (0 conflicts, measured).
__global__ __launch_bounds__(512, 2) void k_gq8(const u8* __restrict__ Ag,
                                                const u8* __restrict__ Bg,
                                                const float* __restrict__ sx,
                                                const float* __restrict__ sw,
                                                float* __restrict__ C,
                                                int M, int N, int K) {
  __shared__ __attribute__((aligned(16))) u8 As[2 * 32768];
  __shared__ __attribute__((aligned(16))) u8 Bs[2 * 32768];
  const int tid  = threadIdx.x;
  const int wave = tid >> 6, lane = tid & 63;
  const int wr = wave >> 2, wc = wave & 3;
  const int m0 = blockIdx.y * 256, n0 = blockIdx.x * 256;
  const int NT = K >> 7;                           // 128-byte K-tiles

  // staging: unit = 64 rows x 128 B = 8 KB = 512 lanes x 16B (1 gload)
  const int srow = tid >> 3;                       // 0..63
  const int csrc = (tid & 7) ^ (srow & 7);         // pre-swizzled source chunk
  const u8* pA = Ag + (size_t)(m0 + srow) * K + csrc * 16;
  const u8* pB = Bg + (size_t)(n0 + srow) * K + csrc * 16;
  const size_t KH = (size_t)128 * K;               // half stride
  const size_t KU = (size_t)64 * K;                // unit stride
  const int wb = wave << 10;                       // wave-uniform LDS base (bytes)

#define SA(nb, h, kt)                                                          \
  do {                                                                         \
    gload_lds16(pA + (h) * KH + (kt),      As + (nb) * 32768 + (h) * 16384 + wb);       \
    gload_lds16(pA + (h) * KH + KU + (kt), As + (nb) * 32768 + (h) * 16384 + 8192 + wb);\
  } while (0)
#define SB(nb, h, kt)                                                          \
  do {                                                                         \
    gload_lds16(pB + (h) * KH + (kt),      Bs + (nb) * 32768 + (h) * 16384 + wb);       \
    gload_lds16(pB + (h) * KH + KU + (kt), Bs + (nb) * 32768 + (h) * 16384 + 8192 + wb);\
  } while (0)

  // fragment reads: row 128 B; phys chunk = (ks*4 + q) ^ (lane&7)
  const int l4 = lane & 15, q = lane >> 4, l7 = lane & 7;
  const int ke0 = (q ^ l7) << 4;                   // bytes; ks=1 -> ke0 ^ 64
  const int aoff = ((wr << 6) + l4) << 7;          // (wr*64 + l4)*128
  const int boff = ((wc << 5) + l4) << 7;          // (wc*32 + l4)*128

  i32x4 acc[8][4] = {};
  i32x4 ar[4][2];      // current A-half [f][ks]
  i32x4 bq[2][2][2];   // both B-halves [nh][g][ks]

#define LDA(buf, mh)                                                           \
  do {                                                                         \
    const u8* b_ = As + (buf) * 32768 + (mh) * 16384 + aoff;                   \
    _Pragma("unroll") for (int f = 0; f < 4; ++f) {                            \
      ar[f][0] = *(const i32x4*)(b_ + f * 2048 + ke0);                         \
      ar[f][1] = *(const i32x4*)(b_ + f * 2048 + (ke0 ^ 64));                  \
    }                                                                          \
  } while (0)
#define LDB(buf, nh)                                                           \
  do {                                                                         \
    const u8* b_ = Bs + (buf) * 32768 + (nh) * 16384 + boff;                   \
    _Pragma("unroll") for (int g = 0; g < 2; ++g) {                            \
      bq[nh][g][0] = *(const i32x4*)(b_ + g * 2048 + ke0);                     \
      bq[nh][g][1] = *(const i32x4*)(b_ + g * 2048 + (ke0 ^ 64));              \
    }                                                                          \
  } while (0)
#define MFMA16(mh, nh)                                                         \
  do {                                                                         \
    __builtin_amdgcn_s_setprio(1);                                             \
    _Pragma("unroll") for (int f = 0; f < 4; ++f)                              \
      _Pragma("unroll") for (int g = 0; g < 2; ++g)                            \
        _Pragma("unroll") for (int ks = 0; ks < 2; ++ks)                       \
          acc[(mh) * 4 + f][(nh) * 2 + g] =                                    \
              __builtin_amdgcn_mfma_i32_16x16x64_i8(                           \
                  ar[f][ks], bq[nh][g][ks], acc[(mh) * 4 + f][(nh) * 2 + g],   \
                  0, 0, 0);                                                    \
    __builtin_amdgcn_s_setprio(0);                                             \
  } while (0)

  // prologue: stage tile 0 in consumption order A0,B0,B1,A1
  SA(0, 0, 0);
  SB(0, 0, 0);
  SB(0, 1, 0);
  SA(0, 1, 0);
  asm volatile("s_waitcnt vmcnt(4)" ::: "memory");   // A0,B0 landed
  __builtin_amdgcn_s_barrier();

  for (int t = 0; t < NT; ++t) {
    const int buf = t & 1, nb = buf ^ 1;
    const int kt1 = (t + 1) << 7;
    const bool st = (t + 1) < NT;

    // ---- ph1: quadrant (0,0); reads A0(8)+B0(4); stages A0(t+1) ----
    LDA(buf, 0);
    LDB(buf, 0);
    if (st) SA(nb, 0, kt1);
    asm volatile("s_waitcnt lgkmcnt(8)" ::: "memory");
    __builtin_amdgcn_s_barrier();
    asm volatile("s_waitcnt lgkmcnt(0)" ::: "memory");
    MFMA16(0, 0);
    if (st) { asm volatile("s_waitcnt vmcnt(4)" ::: "memory"); }
    else    { asm volatile("s_waitcnt vmcnt(2)" ::: "memory"); }
    __builtin_amdgcn_s_barrier();

    // ---- ph2: quadrant (0,1); reads B1(4); stages B0(t+1) ----
    LDB(buf, 1);
    if (st) SB(nb, 0, kt1);
    __builtin_amdgcn_s_barrier();
    asm volatile("s_waitcnt lgkmcnt(0)" ::: "memory");
    MFMA16(0, 1);
    if (st) { asm volatile("s_waitcnt vmcnt(4)" ::: "memory"); }
    else    { asm volatile("s_waitcnt vmcnt(0)" ::: "memory"); }
    __builtin_amdgcn_s_barrier();

    // ---- ph3: quadrant (1,1); reads A1(8); stages B1(t+1) ----
    LDA(buf, 1);
    if (st) SB(nb, 1, kt1);
    __builtin_amdgcn_s_barrier();
    asm volatile("s_waitcnt lgkmcnt(0)" ::: "memory");
    MFMA16(1, 1);
    __builtin_amdgcn_s_barrier();

    // ---- ph4: quadrant (1,0); no reads; stages A1(t+1) ----
    if (st) SA(nb, 1, kt1);
    __builtin_amdgcn_s_barrier();
    MFMA16(1, 0);
    if (st) { asm volatile("s_waitcnt vmcnt(4)" ::: "memory"); }
    __builtin_amdgcn_s_barrier();
  }

  // epilogue: C/D col = lane&15, row = (lane>>4)*4 + reg (dtype-independent)
  float swv[4];
#pragma unroll
  for (int j = 0; j < 4; ++j)
    swv[j] = sw[n0 + (j >> 1) * 128 + wc * 32 + (j & 1) * 16 + l4];
#pragma unroll
  for (int i = 0; i < 8; ++i) {
    const int mh = i >> 2, f = i & 3;
    const int row = m0 + mh * 128 + wr * 64 + f * 16 + q * 4;
#pragma unroll
    for (int j = 0; j < 4; ++j) {
      const int nh = j >> 1, g = j & 1;
      const int col = n0 + nh * 128 + wc * 32 + g * 16 + l4;
#pragma unroll
      for (int v = 0; v < 4; ++v)
        C[(size_t)(row + v) * N + col] = (float)acc[i][j][v] * sx[row + v] * swv[j];
    }
  }
#undef SA
#undef SB
#undef LDA
#undef LDB
#undef MFMA16
}

// ---------------- fallback (generic shapes / no workspace): fp32 tiled ----------------
__global__ __launch_bounds__(256) void k_fallback(const float* __restrict__ X,
                                                  const float* __restrict__ W,
                                                  const float* __restrict__ Am,
                                                  const float* __restrict__ Bm,
                                                  float* __restrict__ C,
                                                  int M, int N, int K) {
  __shared__ float Xs[64][16];
  __shared__ float Ws[64][17];
  const int tid = threadIdx.x;
  const int tn = tid & 15, tm = tid >> 4;
  const int m0 = blockIdx.y * 64, n0 = blockIdx.x * 64;
  float acc[4][4] = {};
  for (int kt = 0; kt < K; kt += 16) {
    __syncthreads();
#pragma unroll
    for (int qq = 0; qq < 4; ++qq) {
      int idx = qq * 256 + tid;
      int r = idx >> 4, c = idx & 15;
      Xs[r][c] = X[(size_t)(m0 + r) * K + kt + c];
      float w = W[(size_t)(n0 + r) * K + kt + c];
      float4 b = *(const float4*)(Bm + ((n0 + r) << 2));
      w += 4.f * (b.x * Am[kt + c] + b.y * Am[4096 + kt + c] +
                  b.z * Am[8192 + kt + c] + b.w * Am[12288 + kt + c]);
      Ws[r][c] = w;
    }
    __syncthreads();
#pragma unroll
    for (int k = 0; k < 16; ++k) {
      float xv[4], wv[4];
#pragma unroll
      for (int i = 0; i < 4; ++i) xv[i] = Xs[tm * 4 + i][k];
#pragma unroll
      for (int j = 0; j < 4; ++j) wv[j] = Ws[tn * 4 + j][k];
#pragma unroll
      for (int i = 0; i < 4; ++i)
#pragma unroll
        for (int j = 0; j < 4; ++j) acc[i][j] += xv[i] * wv[j];
    }
  }
#pragma unroll
  for (int i = 0; i < 4; ++i)
#pragma unroll
    for (int j = 0; j < 4; ++j)
      C[(size_t)(m0 + tm * 4 + i) * N + n0 + tn * 4 + j] = acc[i][j];
}

extern "C" void kernel_launch(void* const* d_in, const int* in_sizes, int n_in,
                              void* d_out, int out_size, void* d_ws, size_t ws_size,
                              hipStream_t stream) {
  const float* x  = (const float*)d_in[0];
  const float* W  = (const float*)d_in[1];
  const float* lA = (const float*)d_in[2];
  const float* lB = (const float*)d_in[3];
  float* out = (float*)d_out;
  const int K = 4096, N = 4096;
  const int M = in_sizes[0] / K;   // 8192
  const size_t need = (size_t)(M + N) * K + (size_t)(M + N) * sizeof(float);

  if (ws_size >= need && (M % 256) == 0) {
    i8* xb = (i8*)d_ws;
    i8* wb = xb + (size_t)M * K;
    float* sx = (float*)(wb + (size_t)N * K);
    float* sw = sx + M;
    k_quant<<<dim3(M + N), dim3(256), 0, stream>>>(x, W, lA, lB, xb, wb, sx, sw, M);
    k_gq8<<<dim3(N / 256, M / 256), dim3(512), 0, stream>>>(
        (const u8*)xb, (const u8*)wb, sx, sw, out, M, N, K);
  } else {
    k_fallback<<<dim3(N / 64, M / 64), dim3(256), 0, stream>>>(x, W, lA, lB, out, M, N, K);
  }
}